// Round 4
// baseline (348.286 us; speedup 1.0000x reference)
//
#include <hip/hip_runtime.h>
#include <cstdint>
#include <cstddef>

#define AS1 __attribute__((address_space(1)))
#define AS3 __attribute__((address_space(3)))

typedef float f32x4 __attribute__((ext_vector_type(4)));
typedef __bf16 bf16x8 __attribute__((ext_vector_type(8)));
typedef __bf16 bf16x4 __attribute__((ext_vector_type(4)));
typedef uint32_t u32x4 __attribute__((ext_vector_type(4)));

// async global->LDS, 16B per lane. LDS dest = wave-uniform base + lane*16.
__device__ __forceinline__ void async_cp16(void* lds, const void* g) {
    __builtin_amdgcn_global_load_lds((AS1 void*)(g), (AS3 void*)(lds), 16, 0, 0);
}

__device__ __forceinline__ bf16x8 frag_of(u32x4 u) {
    return __builtin_bit_cast(bf16x8, u);
}

// ---------------------------------------------------------------- weight cvt
// qkv_w rows are permuted from interleaved (h,{q,k,v},d) to [q(768)|k(768)|v(768)]
// so v-columns form whole 128-col GEMM blocks (enables direct V^T epilogue).
__global__ __launch_bounds__(256)
void cvt_w(const float* __restrict__ qkvw, const float* __restrict__ projw,
           __bf16* __restrict__ qkvwb, __bf16* __restrict__ projwb) {
    int i = blockIdx.x * 256 + threadIdx.x;   // grid 2304*256 = 589824 exactly
    if (i < 442368) {                          // 2304 rows x 192 float4
        int row = i / 192, c4 = (i - row * 192) * 4;
        int t = (row >= 1536) ? 2 : (row >= 768 ? 1 : 0);
        int rem = row - t * 768;
        int hh = rem >> 6, d = rem & 63;
        int in_row = hh * 192 + t * 64 + d;
        float4 v = *(const float4*)(qkvw + (long)in_row * 768 + c4);
        bf16x4 o;
        o[0] = (__bf16)v.x; o[1] = (__bf16)v.y; o[2] = (__bf16)v.z; o[3] = (__bf16)v.w;
        *(bf16x4*)(qkvwb + (long)row * 768 + c4) = o;
    } else {
        int j = i - 442368;                    // 147456 float4 of proj_w
        float4 v = ((const float4*)projw)[j];
        bf16x4 o;
        o[0] = (__bf16)v.x; o[1] = (__bf16)v.y; o[2] = (__bf16)v.z; o[3] = (__bf16)v.w;
        ((bf16x4*)projwb)[j] = o;
    }
}

// ---------------------------------------------------------------- LayerNorm
__global__ __launch_bounds__(256)
void ln_kernel(const float* __restrict__ x, const float* __restrict__ w,
               const float* __restrict__ bsh, __bf16* __restrict__ xn) {
    const int lane = threadIdx.x & 63;
    const long row = (long)blockIdx.x * 4 + (threadIdx.x >> 6);
    const float4* xr = (const float4*)(x + row * 768);
    float4 v[3];
    v[0] = xr[lane]; v[1] = xr[lane + 64]; v[2] = xr[lane + 128];
    float s = 0.f, ss = 0.f;
#pragma unroll
    for (int i = 0; i < 3; ++i) {
        s  += v[i].x + v[i].y + v[i].z + v[i].w;
        ss += v[i].x * v[i].x + v[i].y * v[i].y + v[i].z * v[i].z + v[i].w * v[i].w;
    }
#pragma unroll
    for (int m = 1; m < 64; m <<= 1) { s += __shfl_xor(s, m); ss += __shfl_xor(ss, m); }
    const float mean = s * (1.f / 768.f);
    const float rstd = rsqrtf(ss * (1.f / 768.f) - mean * mean + 1e-5f);
    const float4* wv = (const float4*)w;
    const float4* bv = (const float4*)bsh;
    bf16x4* outp = (bf16x4*)(xn + row * 768);
#pragma unroll
    for (int i = 0; i < 3; ++i) {
        float4 wi = wv[lane + 64 * i], bi = bv[lane + 64 * i];
        bf16x4 o;
        o[0] = (__bf16)((v[i].x - mean) * rstd * wi.x + bi.x);
        o[1] = (__bf16)((v[i].y - mean) * rstd * wi.y + bi.y);
        o[2] = (__bf16)((v[i].z - mean) * rstd * wi.z + bi.z);
        o[3] = (__bf16)((v[i].w - mean) * rstd * wi.w + bi.w);
        outp[lane + 64 * i] = o;
    }
}

// ---------------------------------------------------------------- GEMM core
// C = A @ B^T. MODE 0: qk cols, swapped mfma -> packed b64 (b,h,n,d) stores.
// MODE 2: v cols, normal mfma -> packed b64 V^T (b,h,d,n) stores.
// MODE 1: proj, normal mfma -> fp32 out.
template <int MODE>
__device__ __forceinline__
void gemm_core(__bf16* As, __bf16* Bs,
               const __bf16* __restrict__ A, const __bf16* __restrict__ Bw,
               const float* __restrict__ bias,
               __bf16* __restrict__ q_out, __bf16* __restrict__ k_out,
               __bf16* __restrict__ vt_out, float* __restrict__ f_out,
               long bm, long bn) {
    constexpr int K = 768;
    const int tid  = threadIdx.x;
    const int lane = tid & 63;
    const int quad = lane >> 4;
    const int l16  = lane & 15;
    const int wave = tid >> 6;
    const int wm = wave >> 1, wn = wave & 1;

    const __bf16* Ab = A  + bm * K;
    const __bf16* Bb = Bw + bn * K;

    const int el0 = tid, el1 = tid + 256;
    const int rA0 = el0 >> 2, rA1 = el1 >> 2;
    const int kc  = (tid & 3) * 8;

    f32x4 acc[4][4] = {};

    for (int k0 = 0; k0 < K; k0 += 32) {
        __syncthreads();
        async_cp16((char*)As + el0 * 16, Ab + (long)rA0 * K + (k0 + kc));
        async_cp16((char*)As + el1 * 16, Ab + (long)rA1 * K + (k0 + kc));
        async_cp16((char*)Bs + el0 * 16, Bb + (long)rA0 * K + (k0 + kc));
        async_cp16((char*)Bs + el1 * 16, Bb + (long)rA1 * K + (k0 + kc));
        __syncthreads();

        const u32x4* Av = (const u32x4*)As;
        const u32x4* Bv = (const u32x4*)Bs;
        bf16x8 af[4], bfr[4];
#pragma unroll
        for (int t = 0; t < 4; ++t) {
            af[t]  = frag_of(Av[(wm * 64 + t * 16 + l16) * 4 + quad]);
            bfr[t] = frag_of(Bv[(wn * 64 + t * 16 + l16) * 4 + quad]);
        }
#pragma unroll
        for (int i = 0; i < 4; ++i)
#pragma unroll
            for (int j = 0; j < 4; ++j) {
                if constexpr (MODE == 0)
                    acc[i][j] = __builtin_amdgcn_mfma_f32_16x16x32_bf16(bfr[j], af[i], acc[i][j], 0, 0, 0);
                else
                    acc[i][j] = __builtin_amdgcn_mfma_f32_16x16x32_bf16(af[i], bfr[j], acc[i][j], 0, 0, 0);
            }
    }

    if constexpr (MODE == 0) {
        // swapped: lane row = n (l16-based), 4 consecutive cols per quad
#pragma unroll
        for (int j = 0; j < 4; ++j) {
            int col0 = (int)bn + wn * 64 + j * 16 + quad * 4;   // < 1536
            int t  = col0 >= 768;
            int cc = col0 - t * 768;
            int h  = cc >> 6, d = cc & 63;
            int f  = h * 192 + t * 64 + d;                      // original feature id
            float4 bb = *(const float4*)(bias + f);
            __bf16* dst = t ? k_out : q_out;
#pragma unroll
            for (int i = 0; i < 4; ++i) {
                long row = bm + wm * 64 + i * 16 + l16;
                long b   = row >> 10;
                long n   = row & 1023;
                bf16x4 pk;
                pk[0] = (__bf16)(acc[i][j][0] + bb.x);
                pk[1] = (__bf16)(acc[i][j][1] + bb.y);
                pk[2] = (__bf16)(acc[i][j][2] + bb.z);
                pk[3] = (__bf16)(acc[i][j][3] + bb.w);
                *(bf16x4*)(dst + ((b * 12 + h) * 1024 + n) * 64 + d) = pk;
            }
        }
    } else if constexpr (MODE == 2) {
        // normal: lane col = d (l16-based), 4 consecutive rows (n) per quad
#pragma unroll
        for (int j = 0; j < 4; ++j) {
            int cv = (int)bn - 1536 + wn * 64 + j * 16 + l16;
            int h  = cv >> 6, d = cv & 63;
            float bv = bias[h * 192 + 128 + d];
#pragma unroll
            for (int i = 0; i < 4; ++i) {
                long row0 = bm + wm * 64 + i * 16 + quad * 4;
                long b    = row0 >> 10;
                long n0   = row0 & 1023;
                bf16x4 pk;
                pk[0] = (__bf16)(acc[i][j][0] + bv);
                pk[1] = (__bf16)(acc[i][j][1] + bv);
                pk[2] = (__bf16)(acc[i][j][2] + bv);
                pk[3] = (__bf16)(acc[i][j][3] + bv);
                *(bf16x4*)(vt_out + ((b * 12 + h) * 64 + d) * 1024 + n0) = pk;
            }
        }
    } else {
#pragma unroll
        for (int i = 0; i < 4; ++i) {
#pragma unroll
            for (int r = 0; r < 4; ++r) {
                long row = bm + wm * 64 + i * 16 + quad * 4 + r;
#pragma unroll
                for (int j = 0; j < 4; ++j) {
                    int col = (int)bn + wn * 64 + j * 16 + l16;
                    f_out[row * 768 + col] = acc[i][j][r] + bias[col];
                }
            }
        }
    }
}

__global__ __launch_bounds__(256, 2)
void gemm_qkv(const __bf16* __restrict__ A, const __bf16* __restrict__ Bw,
              const float* __restrict__ bias, __bf16* __restrict__ qb,
              __bf16* __restrict__ kb, __bf16* __restrict__ vtb) {
    __shared__ __align__(16) __bf16 As[128 * 32];
    __shared__ __align__(16) __bf16 Bs[128 * 32];
    int blk = blockIdx.x;
    int bx = blk % 18;
    long by = blk / 18;
    if (bx < 12)
        gemm_core<0>(As, Bs, A, Bw, bias, qb, kb, nullptr, nullptr, by * 128, (long)bx * 128);
    else
        gemm_core<2>(As, Bs, A, Bw, bias, nullptr, nullptr, vtb, nullptr, by * 128, (long)bx * 128);
}

__global__ __launch_bounds__(256, 2)
void gemm_proj(const __bf16* __restrict__ A, const __bf16* __restrict__ Bw,
               const float* __restrict__ bias, float* __restrict__ out) {
    __shared__ __align__(16) __bf16 As[128 * 32];
    __shared__ __align__(16) __bf16 Bs[128 * 32];
    gemm_core<1>(As, Bs, A, Bw, bias, nullptr, nullptr, nullptr, out,
                 (long)blockIdx.y * 128, (long)blockIdx.x * 128);
}

// ---------------------------------------------------------------- flash attention
// block = (qtile of 128, h, b); 4 waves x 32 q-rows (2 groups of 16); k-tiles 64.
// K/V frags read once per wave per k-tile, shared across both q-groups.
// No running max (logits provably small); row-sum deferred. S^T = K*Q^T,
// O^T = V^T*P^T. Q LDS reused as per-wave P (wave's own 32 rows).
__global__ __launch_bounds__(256, 4)
void attn_kernel(const __bf16* __restrict__ Q, const __bf16* __restrict__ Kb,
                 const __bf16* __restrict__ Vt, const float* __restrict__ biases,
                 __bf16* __restrict__ out) {
    __shared__ __align__(16) __bf16 QPs[128 * 64]; // Q tile -> per-wave P
    __shared__ __align__(16) __bf16 Ks[64 * 64];
    __shared__ __align__(16) __bf16 Vts[64 * 64];  // V^T tile [d][kc]
    __shared__ __align__(16) float brow[1024];     // attn_biases[h] * log2(e)

    const int tid  = threadIdx.x;
    const int lane = tid & 63;
    const int wave = tid >> 6;
    const int quad = lane >> 4;
    const int l16  = lane & 15;
    const int sw   = l16 & 7;
    const int qt = blockIdx.x;
    const int h  = blockIdx.y;
    const int b  = blockIdx.z;

    const long bh = (long)b * 12 + h;
    const __bf16* Qg  = Q  + (bh * 1024 + qt * 128) * 64;
    const __bf16* Kg  = Kb + bh * 1024 * 64;
    const __bf16* Vtg = Vt + bh * 64 * 1024;

#pragma unroll
    for (int p = 0; p < 4; ++p) {
        int e = tid + p * 256, r = e >> 3, c = (e & 7) ^ (r & 7);
        async_cp16((char*)QPs + e * 16, Qg + r * 64 + c * 8);
    }
    {
        const float LOG2E = 1.4426950408889634f;
        float4 v = ((const float4*)(biases + (long)h * 1024))[tid];
        float4 o; o.x = v.x * LOG2E; o.y = v.y * LOG2E; o.z = v.z * LOG2E; o.w = v.w * LOG2E;
        ((float4*)brow)[tid] = o;
    }
    __syncthreads();

    bf16x8 aq[2][2];
    {
        const u32x4* Qv = (const u32x4*)QPs;
#pragma unroll
        for (int g = 0; g < 2; ++g) {
            int qrow = wave * 32 + g * 16 + l16;
            aq[g][0] = frag_of(Qv[qrow * 8 + (quad ^ sw)]);
            aq[g][1] = frag_of(Qv[qrow * 8 + ((quad + 4) ^ sw)]);
        }
    }

    const int yq = qt * 4 + wave;             // wave-uniform y of all 32 q-rows
    int pdxb[2][2][4];                        // bias byte offsets, kt-invariant
#pragma unroll
    for (int g = 0; g < 2; ++g)
#pragma unroll
        for (int i2 = 0; i2 < 2; ++i2)
#pragma unroll
            for (int r = 0; r < 4; ++r) {
                int d = (g * 16 + l16) - (i2 * 16 + quad * 4 + r);
                pdxb[g][i2][r] = (d < 0 ? -d : d) * 4;
            }

    const float SSCALE = 0.125f * 1.4426950408889634f;
    float lacc[2] = {0.f, 0.f};
    f32x4 o[2][4] = {};
    __bf16* Psw = QPs + wave * 2048;          // wave's own 32 rows x 64

    const int e0 = tid, e1 = tid + 256;
    const int r0 = e0 >> 3, c0 = (e0 & 7) ^ (r0 & 7);
    const int r1 = e1 >> 3, c1 = (e1 & 7) ^ (r1 & 7);

    for (int kt = 0; kt < 16; ++kt) {
        __syncthreads();
        {
            const __bf16* Kt  = Kg + kt * 4096;
            const __bf16* Vtt = Vtg + kt * 64;
            async_cp16((char*)Ks + e0 * 16, Kt + r0 * 64 + c0 * 8);
            async_cp16((char*)Ks + e1 * 16, Kt + r1 * 64 + c1 * 8);
            async_cp16((char*)Vts + e0 * 16, Vtt + r0 * 1024 + c0 * 8);
            async_cp16((char*)Vts + e1 * 16, Vtt + r1 * 1024 + c1 * 8);
        }
        __syncthreads();

        // S^T = K * Q^T for both q-groups; K frags shared
        f32x4 s[2][4];
        const u32x4* Kv = (const u32x4*)Ks;
#pragma unroll
        for (int nt = 0; nt < 4; ++nt) {
            int krow = nt * 16 + l16;
            bf16x8 k0 = frag_of(Kv[krow * 8 + (quad ^ sw)]);
            bf16x8 k1 = frag_of(Kv[krow * 8 + ((quad + 4) ^ sw)]);
#pragma unroll
            for (int g = 0; g < 2; ++g) {
                f32x4 z = {0.f, 0.f, 0.f, 0.f};
                z = __builtin_amdgcn_mfma_f32_16x16x32_bf16(k0, aq[g][0], z, 0, 0, 0);
                z = __builtin_amdgcn_mfma_f32_16x16x32_bf16(k1, aq[g][1], z, 0, 0, 0);
                s[g][nt] = z;
            }
        }

        int dy0 = yq - 2 * kt;     dy0 = dy0 < 0 ? -dy0 : dy0;
        int dy1 = yq - 2 * kt - 1; dy1 = dy1 < 0 ? -dy1 : dy1;
        const char* br0 = (const char*)(brow + dy0 * 32);
        const char* br1 = (const char*)(brow + dy1 * 32);
#pragma unroll
        for (int g = 0; g < 2; ++g) {
            int rowb = (g * 16 + l16) * 128 + (quad & 1) * 8;
#pragma unroll
            for (int nt = 0; nt < 4; ++nt) {
                const char* br = (nt & 2) ? br1 : br0;
                bf16x4 pk;
#pragma unroll
                for (int r = 0; r < 4; ++r) {
                    float bvv = *(const float*)(br + pdxb[g][nt & 1][r]);
                    float p = __builtin_amdgcn_exp2f(s[g][nt][r] * SSCALE + bvv);
                    lacc[g] += p;
                    pk[r] = (__bf16)p;
                }
                *(bf16x4*)((char*)Psw + rowb + (((nt * 2 + (quad >> 1)) ^ sw) << 4)) = pk;
            }
        }

        // O^T = V^T * P^T; V frags shared across q-groups
        const u32x4* Pv = (const u32x4*)Psw;
        const u32x4* Vv = (const u32x4*)Vts;
        bf16x8 bp[2][2];
#pragma unroll
        for (int g = 0; g < 2; ++g) {
            int prow = g * 16 + l16;
            bp[g][0] = frag_of(Pv[prow * 8 + (quad ^ sw)]);
            bp[g][1] = frag_of(Pv[prow * 8 + ((quad + 4) ^ sw)]);
        }
#pragma unroll
        for (int dt = 0; dt < 4; ++dt) {
            int vrow = dt * 16 + l16;
            bf16x8 v0 = frag_of(Vv[vrow * 8 + (quad ^ sw)]);
            bf16x8 v1 = frag_of(Vv[vrow * 8 + ((quad + 4) ^ sw)]);
#pragma unroll
            for (int g = 0; g < 2; ++g) {
                o[g][dt] = __builtin_amdgcn_mfma_f32_16x16x32_bf16(v0, bp[g][0], o[g][dt], 0, 0, 0);
                o[g][dt] = __builtin_amdgcn_mfma_f32_16x16x32_bf16(v1, bp[g][1], o[g][dt], 0, 0, 0);
            }
        }
    }

#pragma unroll
    for (int g = 0; g < 2; ++g) {
        float l = lacc[g];
        l += __shfl_xor(l, 16);
        l += __shfl_xor(l, 32);
        const float rl = 1.f / l;
        const long n = qt * 128 + wave * 32 + g * 16 + l16;
        __bf16* op = out + ((long)b * 1024 + n) * 768 + h * 64 + quad * 4;
#pragma unroll
        for (int dt = 0; dt < 4; ++dt) {
            bf16x4 ov;
            ov[0] = (__bf16)(o[g][dt][0] * rl);
            ov[1] = (__bf16)(o[g][dt][1] * rl);
            ov[2] = (__bf16)(o[g][dt][2] * rl);
            ov[3] = (__bf16)(o[g][dt][3] * rl);
            *(bf16x4*)(op + dt * 16) = ov;
        }
    }
}

// ---------------------------------------------------------------- launch
extern "C" void kernel_launch(void* const* d_in, const int* in_sizes, int n_in,
                              void* d_out, int out_size, void* d_ws, size_t ws_size,
                              hipStream_t stream) {
    (void)in_sizes; (void)n_in; (void)out_size; (void)ws_size;
    const float* x      = (const float*)d_in[0];
    const float* ln_w   = (const float*)d_in[1];
    const float* ln_b   = (const float*)d_in[2];
    const float* qkv_w  = (const float*)d_in[3];
    const float* qkv_b  = (const float*)d_in[4];
    const float* proj_w = (const float*)d_in[5];
    const float* proj_b = (const float*)d_in[6];
    const float* ab     = (const float*)d_in[7];
    float* outp = (float*)d_out;

    char* ws = (char*)d_ws;
    __bf16* xn     = (__bf16*)(ws);               // reused as attn output
    __bf16* aout   = (__bf16*)(ws);
    __bf16* qkvwb  = (__bf16*)(ws + 25165824);
    __bf16* projwb = (__bf16*)(ws + 28704768);
    __bf16* qb     = (__bf16*)(ws + 29884416);
    __bf16* kb     = (__bf16*)(ws + 55050240);
    __bf16* vtb    = (__bf16*)(ws + 80216064);    // V^T (b,h,d,n), direct from GEMM

    cvt_w<<<2304, 256, 0, stream>>>(qkv_w, proj_w, qkvwb, projwb);
    ln_kernel<<<4096, 256, 0, stream>>>(x, ln_w, ln_b, xn);
    gemm_qkv<<<2304, 256, 0, stream>>>(xn, qkvwb, qkv_b, qb, kb, vtb);
    attn_kernel<<<dim3(8, 12, 16), 256, 0, stream>>>(qb, kb, vtb, ab, aout);
    gemm_proj<<<dim3(6, 128), 256, 0, stream>>>(aout, projwb, proj_b, outp);
}

// Round 5
// 333.695 us; speedup vs baseline: 1.0437x; 1.0437x over previous
//
#include <hip/hip_runtime.h>
#include <cstdint>
#include <cstddef>

#define AS1 __attribute__((address_space(1)))
#define AS3 __attribute__((address_space(3)))

typedef float f32x4 __attribute__((ext_vector_type(4)));
typedef __bf16 bf16x8 __attribute__((ext_vector_type(8)));
typedef __bf16 bf16x4 __attribute__((ext_vector_type(4)));
typedef _Float16 h16x4 __attribute__((ext_vector_type(4)));
typedef uint32_t u32x4 __attribute__((ext_vector_type(4)));

// async global->LDS, 16B per lane. LDS dest = wave-uniform base + lane*16.
__device__ __forceinline__ void async_cp16(void* lds, const void* g) {
    __builtin_amdgcn_global_load_lds((AS1 void*)(g), (AS3 void*)(lds), 16, 0, 0);
}

__device__ __forceinline__ bf16x8 frag_of(u32x4 u) {
    return __builtin_bit_cast(bf16x8, u);
}

// ---------------------------------------------------------------- weight cvt
// qkv_w rows permuted from interleaved (h,{q,k,v},d) to [q(768)|k(768)|v(768)]
// so v-columns form whole 128-col GEMM blocks (enables direct V^T epilogue).
__global__ __launch_bounds__(256)
void cvt_w(const float* __restrict__ qkvw, const float* __restrict__ projw,
           __bf16* __restrict__ qkvwb, __bf16* __restrict__ projwb) {
    int i = blockIdx.x * 256 + threadIdx.x;   // grid 2304*256 = 589824 exactly
    if (i < 442368) {                          // 2304 rows x 192 float4
        int row = i / 192, c4 = (i - row * 192) * 4;
        int t = (row >= 1536) ? 2 : (row >= 768 ? 1 : 0);
        int rem = row - t * 768;
        int hh = rem >> 6, d = rem & 63;
        int in_row = hh * 192 + t * 64 + d;
        float4 v = *(const float4*)(qkvw + (long)in_row * 768 + c4);
        bf16x4 o;
        o[0] = (__bf16)v.x; o[1] = (__bf16)v.y; o[2] = (__bf16)v.z; o[3] = (__bf16)v.w;
        *(bf16x4*)(qkvwb + (long)row * 768 + c4) = o;
    } else {
        int j = i - 442368;                    // 147456 float4 of proj_w
        float4 v = ((const float4*)projw)[j];
        bf16x4 o;
        o[0] = (__bf16)v.x; o[1] = (__bf16)v.y; o[2] = (__bf16)v.z; o[3] = (__bf16)v.w;
        ((bf16x4*)projwb)[j] = o;
    }
}

// ---------------------------------------------------------------- LayerNorm
__global__ __launch_bounds__(256)
void ln_kernel(const float* __restrict__ x, const float* __restrict__ w,
               const float* __restrict__ bsh, __bf16* __restrict__ xn) {
    const int lane = threadIdx.x & 63;
    const long row = (long)blockIdx.x * 4 + (threadIdx.x >> 6);
    const float4* xr = (const float4*)(x + row * 768);
    float4 v[3];
    v[0] = xr[lane]; v[1] = xr[lane + 64]; v[2] = xr[lane + 128];
    float s = 0.f, ss = 0.f;
#pragma unroll
    for (int i = 0; i < 3; ++i) {
        s  += v[i].x + v[i].y + v[i].z + v[i].w;
        ss += v[i].x * v[i].x + v[i].y * v[i].y + v[i].z * v[i].z + v[i].w * v[i].w;
    }
#pragma unroll
    for (int m = 1; m < 64; m <<= 1) { s += __shfl_xor(s, m); ss += __shfl_xor(ss, m); }
    const float mean = s * (1.f / 768.f);
    const float rstd = rsqrtf(ss * (1.f / 768.f) - mean * mean + 1e-5f);
    const float4* wv = (const float4*)w;
    const float4* bv = (const float4*)bsh;
    bf16x4* outp = (bf16x4*)(xn + row * 768);
#pragma unroll
    for (int i = 0; i < 3; ++i) {
        float4 wi = wv[lane + 64 * i], bi = bv[lane + 64 * i];
        bf16x4 o;
        o[0] = (__bf16)((v[i].x - mean) * rstd * wi.x + bi.x);
        o[1] = (__bf16)((v[i].y - mean) * rstd * wi.y + bi.y);
        o[2] = (__bf16)((v[i].z - mean) * rstd * wi.z + bi.z);
        o[3] = (__bf16)((v[i].w - mean) * rstd * wi.w + bi.w);
        outp[lane + 64 * i] = o;
    }
}

// ---------------------------------------------------------------- GEMM core
// C = A @ B^T. MODE 0: qk cols, swapped mfma -> packed b64 (b,h,n,d) stores.
// MODE 2: v cols, normal mfma -> packed b64 V^T (b,h,d,n) stores.
// MODE 1: proj, normal mfma -> fp32 out.
template <int MODE>
__device__ __forceinline__
void gemm_core(__bf16* As, __bf16* Bs,
               const __bf16* __restrict__ A, const __bf16* __restrict__ Bw,
               const float* __restrict__ bias,
               __bf16* __restrict__ q_out, __bf16* __restrict__ k_out,
               __bf16* __restrict__ vt_out, float* __restrict__ f_out,
               long bm, long bn) {
    constexpr int K = 768;
    const int tid  = threadIdx.x;
    const int lane = tid & 63;
    const int quad = lane >> 4;
    const int l16  = lane & 15;
    const int wave = tid >> 6;
    const int wm = wave >> 1, wn = wave & 1;

    const __bf16* Ab = A  + bm * K;
    const __bf16* Bb = Bw + bn * K;

    const int el0 = tid, el1 = tid + 256;
    const int rA0 = el0 >> 2, rA1 = el1 >> 2;
    const int kc  = (tid & 3) * 8;

    f32x4 acc[4][4] = {};

    for (int k0 = 0; k0 < K; k0 += 32) {
        __syncthreads();
        async_cp16((char*)As + el0 * 16, Ab + (long)rA0 * K + (k0 + kc));
        async_cp16((char*)As + el1 * 16, Ab + (long)rA1 * K + (k0 + kc));
        async_cp16((char*)Bs + el0 * 16, Bb + (long)rA0 * K + (k0 + kc));
        async_cp16((char*)Bs + el1 * 16, Bb + (long)rA1 * K + (k0 + kc));
        __syncthreads();

        const u32x4* Av = (const u32x4*)As;
        const u32x4* Bv = (const u32x4*)Bs;
        bf16x8 af[4], bfr[4];
#pragma unroll
        for (int t = 0; t < 4; ++t) {
            af[t]  = frag_of(Av[(wm * 64 + t * 16 + l16) * 4 + quad]);
            bfr[t] = frag_of(Bv[(wn * 64 + t * 16 + l16) * 4 + quad]);
        }
#pragma unroll
        for (int i = 0; i < 4; ++i)
#pragma unroll
            for (int j = 0; j < 4; ++j) {
                if constexpr (MODE == 0)
                    acc[i][j] = __builtin_amdgcn_mfma_f32_16x16x32_bf16(bfr[j], af[i], acc[i][j], 0, 0, 0);
                else
                    acc[i][j] = __builtin_amdgcn_mfma_f32_16x16x32_bf16(af[i], bfr[j], acc[i][j], 0, 0, 0);
            }
    }

    if constexpr (MODE == 0) {
        // swapped: lane row = n (l16-based), 4 consecutive cols per quad
#pragma unroll
        for (int j = 0; j < 4; ++j) {
            int col0 = (int)bn + wn * 64 + j * 16 + quad * 4;   // < 1536
            int t  = col0 >= 768;
            int cc = col0 - t * 768;
            int h  = cc >> 6, d = cc & 63;
            int f  = h * 192 + t * 64 + d;                      // original feature id
            float4 bb = *(const float4*)(bias + f);
            __bf16* dst = t ? k_out : q_out;
#pragma unroll
            for (int i = 0; i < 4; ++i) {
                long row = bm + wm * 64 + i * 16 + l16;
                long b   = row >> 10;
                long n   = row & 1023;
                bf16x4 pk;
                pk[0] = (__bf16)(acc[i][j][0] + bb.x);
                pk[1] = (__bf16)(acc[i][j][1] + bb.y);
                pk[2] = (__bf16)(acc[i][j][2] + bb.z);
                pk[3] = (__bf16)(acc[i][j][3] + bb.w);
                *(bf16x4*)(dst + ((b * 12 + h) * 1024 + n) * 64 + d) = pk;
            }
        }
    } else if constexpr (MODE == 2) {
        // normal: lane col = d (l16-based), 4 consecutive rows (n) per quad
#pragma unroll
        for (int j = 0; j < 4; ++j) {
            int cv = (int)bn - 1536 + wn * 64 + j * 16 + l16;
            int h  = cv >> 6, d = cv & 63;
            float bv = bias[h * 192 + 128 + d];
#pragma unroll
            for (int i = 0; i < 4; ++i) {
                long row0 = bm + wm * 64 + i * 16 + quad * 4;
                long b    = row0 >> 10;
                long n0   = row0 & 1023;
                bf16x4 pk;
                pk[0] = (__bf16)(acc[i][j][0] + bv);
                pk[1] = (__bf16)(acc[i][j][1] + bv);
                pk[2] = (__bf16)(acc[i][j][2] + bv);
                pk[3] = (__bf16)(acc[i][j][3] + bv);
                *(bf16x4*)(vt_out + ((b * 12 + h) * 64 + d) * 1024 + n0) = pk;
            }
        }
    } else {
#pragma unroll
        for (int i = 0; i < 4; ++i) {
#pragma unroll
            for (int r = 0; r < 4; ++r) {
                long row = bm + wm * 64 + i * 16 + quad * 4 + r;
#pragma unroll
                for (int j = 0; j < 4; ++j) {
                    int col = (int)bn + wn * 64 + j * 16 + l16;
                    f_out[row * 768 + col] = acc[i][j][r] + bias[col];
                }
            }
        }
    }
}

__global__ __launch_bounds__(256, 3)
void gemm_qkv(const __bf16* __restrict__ A, const __bf16* __restrict__ Bw,
              const float* __restrict__ bias, __bf16* __restrict__ qb,
              __bf16* __restrict__ kb, __bf16* __restrict__ vtb) {
    __shared__ __align__(16) __bf16 As[128 * 32];
    __shared__ __align__(16) __bf16 Bs[128 * 32];
    int blk = blockIdx.x;
    int bx = blk % 18;
    long by = blk / 18;
    if (bx < 12)
        gemm_core<0>(As, Bs, A, Bw, bias, qb, kb, nullptr, nullptr, by * 128, (long)bx * 128);
    else
        gemm_core<2>(As, Bs, A, Bw, bias, nullptr, nullptr, vtb, nullptr, by * 128, (long)bx * 128);
}

__global__ __launch_bounds__(256, 3)
void gemm_proj(const __bf16* __restrict__ A, const __bf16* __restrict__ Bw,
               const float* __restrict__ bias, float* __restrict__ out) {
    __shared__ __align__(16) __bf16 As[128 * 32];
    __shared__ __align__(16) __bf16 Bs[128 * 32];
    gemm_core<1>(As, Bs, A, Bw, bias, nullptr, nullptr, nullptr, out,
                 (long)blockIdx.y * 128, (long)blockIdx.x * 128);
}

// ---------------------------------------------------------------- flash attention
// block = (qtile of 64, h, b); 4 waves x 16 q-rows; k-tiles 64.
// No running max (logits provably small); row-sum deferred. S^T = K*Q^T,
// O^T = V^T*P^T. Q LDS reused as per-wave P. Bias row cached in LDS as f16
// (26.6 KB total LDS -> 6 blocks/CU with launch_bounds(256,6); VGPR ~44 <= 85).
__global__ __launch_bounds__(256, 6)
void attn_kernel(const __bf16* __restrict__ Q, const __bf16* __restrict__ Kb,
                 const __bf16* __restrict__ Vt, const float* __restrict__ biases,
                 __bf16* __restrict__ out) {
    __shared__ __align__(16) __bf16 QPs[64 * 64];  // Q tile, then per-wave P
    __shared__ __align__(16) __bf16 Ks[64 * 64];
    __shared__ __align__(16) __bf16 Vts[64 * 64];  // V^T tile [d][kc]
    __shared__ __align__(16) _Float16 brow[1024];  // attn_biases[h] * log2(e), f16

    const int tid  = threadIdx.x;
    const int lane = tid & 63;
    const int wave = tid >> 6;
    const int quad = lane >> 4;
    const int l16  = lane & 15;
    const int sw   = l16 & 7;
    const int qt = blockIdx.x;
    const int h  = blockIdx.y;
    const int b  = blockIdx.z;

    const long bh = (long)b * 12 + h;
    const __bf16* Qg  = Q  + (bh * 1024 + qt * 64) * 64;
    const __bf16* Kg  = Kb + bh * 1024 * 64;
    const __bf16* Vtg = Vt + bh * 64 * 1024;

    const int e0 = tid, e1 = tid + 256;
    const int r0 = e0 >> 3, c0 = (e0 & 7) ^ (r0 & 7);
    const int r1 = e1 >> 3, c1 = (e1 & 7) ^ (r1 & 7);

    async_cp16((char*)QPs + e0 * 16, Qg + r0 * 64 + c0 * 8);
    async_cp16((char*)QPs + e1 * 16, Qg + r1 * 64 + c1 * 8);
    {
        const float LOG2E = 1.4426950408889634f;
        float4 v = ((const float4*)(biases + (long)h * 1024))[tid];
        h16x4 o;
        o[0] = (_Float16)(v.x * LOG2E); o[1] = (_Float16)(v.y * LOG2E);
        o[2] = (_Float16)(v.z * LOG2E); o[3] = (_Float16)(v.w * LOG2E);
        *(h16x4*)(brow + tid * 4) = o;
    }
    __syncthreads();

    // Q b-frags (lane l16 = q-row wave*16+l16), cached across the loop
    bf16x8 aq[2];
    {
        const u32x4* Qv = (const u32x4*)QPs;
        int qrow = wave * 16 + l16;
        aq[0] = frag_of(Qv[qrow * 8 + (quad ^ sw)]);
        aq[1] = frag_of(Qv[qrow * 8 + ((quad + 4) ^ sw)]);
    }

    // relative-position precompute: yq wave-uniform, xq per-lane (kt-invariant)
    const int yq = 2 * qt + (wave >> 1);
    const int xq = ((wave & 1) << 4) + l16;
    int pdx[2][4];
#pragma unroll
    for (int i2 = 0; i2 < 2; ++i2)
#pragma unroll
        for (int r = 0; r < 4; ++r) {
            int xk = (i2 << 4) + quad * 4 + r;
            int d = xq - xk; pdx[i2][r] = d < 0 ? -d : d;
        }

    const float SSCALE = 0.125f * 1.4426950408889634f;
    float lacc = 0.f;
    f32x4 o[4] = {};
    __bf16* Psw = QPs + wave * 1024;           // 16 rows x 64, per-wave
    const int pwb = l16 * 128 + (quad & 1) * 8; // P-write byte base

    for (int kt = 0; kt < 16; ++kt) {
        __syncthreads();
        {
            const __bf16* Kt  = Kg + kt * 4096;
            const __bf16* Vtt = Vtg + kt * 64;
            async_cp16((char*)Ks + e0 * 16, Kt + r0 * 64 + c0 * 8);
            async_cp16((char*)Ks + e1 * 16, Kt + r1 * 64 + c1 * 8);
            async_cp16((char*)Vts + e0 * 16, Vtt + r0 * 1024 + c0 * 8);
            async_cp16((char*)Vts + e1 * 16, Vtt + r1 * 1024 + c1 * 8);
        }
        __syncthreads();

        // S^T = K * Q^T : s[nt][r] = S[qrow=l16][k = kt*64 + nt*16 + quad*4 + r]
        f32x4 s[4];
        const u32x4* Kv = (const u32x4*)Ks;
#pragma unroll
        for (int nt = 0; nt < 4; ++nt) {
            int krow = nt * 16 + l16;
            bf16x8 k0 = frag_of(Kv[krow * 8 + (quad ^ sw)]);
            bf16x8 k1 = frag_of(Kv[krow * 8 + ((quad + 4) ^ sw)]);
            f32x4 z = {0.f, 0.f, 0.f, 0.f};
            z = __builtin_amdgcn_mfma_f32_16x16x32_bf16(k0, aq[0], z, 0, 0, 0);
            z = __builtin_amdgcn_mfma_f32_16x16x32_bf16(k1, aq[1], z, 0, 0, 0);
            s[nt] = z;
        }

        int dy0 = yq - 2 * kt;     dy0 = dy0 < 0 ? -dy0 : dy0;
        int dy1 = yq - 2 * kt - 1; dy1 = dy1 < 0 ? -dy1 : dy1;
        const _Float16* br0 = brow + dy0 * 32;
        const _Float16* br1 = brow + dy1 * 32;
#pragma unroll
        for (int nt = 0; nt < 4; ++nt) {
            const _Float16* br = (nt & 2) ? br1 : br0;
            bf16x4 pk;
#pragma unroll
            for (int r = 0; r < 4; ++r) {
                float p = __builtin_amdgcn_exp2f(s[nt][r] * SSCALE + (float)br[pdx[nt & 1][r]]);
                lacc += p;
                pk[r] = (__bf16)p;
            }
            *(bf16x4*)((char*)Psw + pwb + (((nt * 2 + (quad >> 1)) ^ sw) << 4)) = pk;
        }

        // O^T = V^T * P^T : o[dt][r] = O[qrow=l16][d = dt*16 + quad*4 + r]
        const u32x4* Pv = (const u32x4*)Psw;
        const u32x4* Vv = (const u32x4*)Vts;
        bf16x8 bp0 = frag_of(Pv[l16 * 8 + (quad ^ sw)]);
        bf16x8 bp1 = frag_of(Pv[l16 * 8 + ((quad + 4) ^ sw)]);
#pragma unroll
        for (int dt = 0; dt < 4; ++dt) {
            int vrow = dt * 16 + l16;
            bf16x8 v0 = frag_of(Vv[vrow * 8 + (quad ^ sw)]);
            bf16x8 v1 = frag_of(Vv[vrow * 8 + ((quad + 4) ^ sw)]);
            o[dt] = __builtin_amdgcn_mfma_f32_16x16x32_bf16(v0, bp0, o[dt], 0, 0, 0);
            o[dt] = __builtin_amdgcn_mfma_f32_16x16x32_bf16(v1, bp1, o[dt], 0, 0, 0);
        }
    }

    // deferred row-sum: combine the 4 quads holding the same q-row
    lacc += __shfl_xor(lacc, 16);
    lacc += __shfl_xor(lacc, 32);
    const float rl = 1.f / lacc;

    const long n = qt * 64 + wave * 16 + l16;
    __bf16* op = out + ((long)b * 1024 + n) * 768 + h * 64 + quad * 4;
#pragma unroll
    for (int dt = 0; dt < 4; ++dt) {
        bf16x4 ov;
        ov[0] = (__bf16)(o[dt][0] * rl);
        ov[1] = (__bf16)(o[dt][1] * rl);
        ov[2] = (__bf16)(o[dt][2] * rl);
        ov[3] = (__bf16)(o[dt][3] * rl);
        *(bf16x4*)(op + dt * 16) = ov;
    }
}

// ---------------------------------------------------------------- launch
extern "C" void kernel_launch(void* const* d_in, const int* in_sizes, int n_in,
                              void* d_out, int out_size, void* d_ws, size_t ws_size,
                              hipStream_t stream) {
    (void)in_sizes; (void)n_in; (void)out_size; (void)ws_size;
    const float* x      = (const float*)d_in[0];
    const float* ln_w   = (const float*)d_in[1];
    const float* ln_b   = (const float*)d_in[2];
    const float* qkv_w  = (const float*)d_in[3];
    const float* qkv_b  = (const float*)d_in[4];
    const float* proj_w = (const float*)d_in[5];
    const float* proj_b = (const float*)d_in[6];
    const float* ab     = (const float*)d_in[7];
    float* outp = (float*)d_out;

    char* ws = (char*)d_ws;
    __bf16* xn     = (__bf16*)(ws);               // reused as attn output
    __bf16* aout   = (__bf16*)(ws);
    __bf16* qkvwb  = (__bf16*)(ws + 25165824);
    __bf16* projwb = (__bf16*)(ws + 28704768);
    __bf16* qb     = (__bf16*)(ws + 29884416);
    __bf16* kb     = (__bf16*)(ws + 55050240);
    __bf16* vtb    = (__bf16*)(ws + 80216064);    // V^T (b,h,d,n), direct from GEMM

    cvt_w<<<2304, 256, 0, stream>>>(qkv_w, proj_w, qkvwb, projwb);
    ln_kernel<<<4096, 256, 0, stream>>>(x, ln_w, ln_b, xn);
    gemm_qkv<<<2304, 256, 0, stream>>>(xn, qkvwb, qkv_b, qb, kb, vtb);
    attn_kernel<<<dim3(16, 12, 16), 256, 0, stream>>>(qb, kb, vtb, ab, aout);
    gemm_proj<<<dim3(6, 128), 256, 0, stream>>>(aout, projwb, proj_b, outp);
}

// Round 6
// 326.414 us; speedup vs baseline: 1.0670x; 1.0223x over previous
//
#include <hip/hip_runtime.h>
#include <cstdint>
#include <cstddef>

#define AS1 __attribute__((address_space(1)))
#define AS3 __attribute__((address_space(3)))

typedef float f32x4 __attribute__((ext_vector_type(4)));
typedef __bf16 bf16x8 __attribute__((ext_vector_type(8)));
typedef __bf16 bf16x4 __attribute__((ext_vector_type(4)));
typedef _Float16 h16x4 __attribute__((ext_vector_type(4)));
typedef uint32_t u32x4 __attribute__((ext_vector_type(4)));

// async global->LDS, 16B per lane. LDS dest = wave-uniform base + lane*16.
__device__ __forceinline__ void async_cp16(void* lds, const void* g) {
    __builtin_amdgcn_global_load_lds((AS1 void*)(g), (AS3 void*)(lds), 16, 0, 0);
}

__device__ __forceinline__ bf16x8 frag_of(u32x4 u) {
    return __builtin_bit_cast(bf16x8, u);
}

// ---------------------------------------------------------------- weight cvt
// qkv_w rows permuted from interleaved (h,{q,k,v},d) to [q(768)|k(768)|v(768)]
// so v-columns form whole 128-col GEMM blocks (enables direct V^T epilogue).
__global__ __launch_bounds__(256)
void cvt_w(const float* __restrict__ qkvw, const float* __restrict__ projw,
           __bf16* __restrict__ qkvwb, __bf16* __restrict__ projwb) {
    int i = blockIdx.x * 256 + threadIdx.x;   // grid 2304*256 = 589824 exactly
    if (i < 442368) {                          // 2304 rows x 192 float4
        int row = i / 192, c4 = (i - row * 192) * 4;
        int t = (row >= 1536) ? 2 : (row >= 768 ? 1 : 0);
        int rem = row - t * 768;
        int hh = rem >> 6, d = rem & 63;
        int in_row = hh * 192 + t * 64 + d;
        float4 v = *(const float4*)(qkvw + (long)in_row * 768 + c4);
        bf16x4 o;
        o[0] = (__bf16)v.x; o[1] = (__bf16)v.y; o[2] = (__bf16)v.z; o[3] = (__bf16)v.w;
        *(bf16x4*)(qkvwb + (long)row * 768 + c4) = o;
    } else {
        int j = i - 442368;                    // 147456 float4 of proj_w
        float4 v = ((const float4*)projw)[j];
        bf16x4 o;
        o[0] = (__bf16)v.x; o[1] = (__bf16)v.y; o[2] = (__bf16)v.z; o[3] = (__bf16)v.w;
        ((bf16x4*)projwb)[j] = o;
    }
}

// ---------------------------------------------------------------- LayerNorm
__global__ __launch_bounds__(256)
void ln_kernel(const float* __restrict__ x, const float* __restrict__ w,
               const float* __restrict__ bsh, __bf16* __restrict__ xn) {
    const int lane = threadIdx.x & 63;
    const long row = (long)blockIdx.x * 4 + (threadIdx.x >> 6);
    const float4* xr = (const float4*)(x + row * 768);
    float4 v[3];
    v[0] = xr[lane]; v[1] = xr[lane + 64]; v[2] = xr[lane + 128];
    float s = 0.f, ss = 0.f;
#pragma unroll
    for (int i = 0; i < 3; ++i) {
        s  += v[i].x + v[i].y + v[i].z + v[i].w;
        ss += v[i].x * v[i].x + v[i].y * v[i].y + v[i].z * v[i].z + v[i].w * v[i].w;
    }
#pragma unroll
    for (int m = 1; m < 64; m <<= 1) { s += __shfl_xor(s, m); ss += __shfl_xor(ss, m); }
    const float mean = s * (1.f / 768.f);
    const float rstd = rsqrtf(ss * (1.f / 768.f) - mean * mean + 1e-5f);
    const float4* wv = (const float4*)w;
    const float4* bv = (const float4*)bsh;
    bf16x4* outp = (bf16x4*)(xn + row * 768);
#pragma unroll
    for (int i = 0; i < 3; ++i) {
        float4 wi = wv[lane + 64 * i], bi = bv[lane + 64 * i];
        bf16x4 o;
        o[0] = (__bf16)((v[i].x - mean) * rstd * wi.x + bi.x);
        o[1] = (__bf16)((v[i].y - mean) * rstd * wi.y + bi.y);
        o[2] = (__bf16)((v[i].z - mean) * rstd * wi.z + bi.z);
        o[3] = (__bf16)((v[i].w - mean) * rstd * wi.w + bi.w);
        outp[lane + 64 * i] = o;
    }
}

// ---------------------------------------------------------------- GEMM core
// C = A @ B^T. MODE 0: qk cols, swapped mfma -> packed b64 (b,h,n,d) stores.
// MODE 2: v cols, normal mfma -> packed b64 V^T (b,h,d,n) stores.
// MODE 1: proj, normal mfma -> fp32 out.
template <int MODE>
__device__ __forceinline__
void gemm_core(__bf16* As, __bf16* Bs,
               const __bf16* __restrict__ A, const __bf16* __restrict__ Bw,
               const float* __restrict__ bias,
               __bf16* __restrict__ q_out, __bf16* __restrict__ k_out,
               __bf16* __restrict__ vt_out, float* __restrict__ f_out,
               long bm, long bn) {
    constexpr int K = 768;
    const int tid  = threadIdx.x;
    const int lane = tid & 63;
    const int quad = lane >> 4;
    const int l16  = lane & 15;
    const int wave = tid >> 6;
    const int wm = wave >> 1, wn = wave & 1;

    const __bf16* Ab = A  + bm * K;
    const __bf16* Bb = Bw + bn * K;

    const int el0 = tid, el1 = tid + 256;
    const int rA0 = el0 >> 2, rA1 = el1 >> 2;
    const int kc  = (tid & 3) * 8;

    f32x4 acc[4][4] = {};

    for (int k0 = 0; k0 < K; k0 += 32) {
        __syncthreads();
        async_cp16((char*)As + el0 * 16, Ab + (long)rA0 * K + (k0 + kc));
        async_cp16((char*)As + el1 * 16, Ab + (long)rA1 * K + (k0 + kc));
        async_cp16((char*)Bs + el0 * 16, Bb + (long)rA0 * K + (k0 + kc));
        async_cp16((char*)Bs + el1 * 16, Bb + (long)rA1 * K + (k0 + kc));
        __syncthreads();

        const u32x4* Av = (const u32x4*)As;
        const u32x4* Bv = (const u32x4*)Bs;
        bf16x8 af[4], bfr[4];
#pragma unroll
        for (int t = 0; t < 4; ++t) {
            af[t]  = frag_of(Av[(wm * 64 + t * 16 + l16) * 4 + quad]);
            bfr[t] = frag_of(Bv[(wn * 64 + t * 16 + l16) * 4 + quad]);
        }
#pragma unroll
        for (int i = 0; i < 4; ++i)
#pragma unroll
            for (int j = 0; j < 4; ++j) {
                if constexpr (MODE == 0)
                    acc[i][j] = __builtin_amdgcn_mfma_f32_16x16x32_bf16(bfr[j], af[i], acc[i][j], 0, 0, 0);
                else
                    acc[i][j] = __builtin_amdgcn_mfma_f32_16x16x32_bf16(af[i], bfr[j], acc[i][j], 0, 0, 0);
            }
    }

    if constexpr (MODE == 0) {
        // swapped: lane row = n (l16-based), 4 consecutive cols per quad
#pragma unroll
        for (int j = 0; j < 4; ++j) {
            int col0 = (int)bn + wn * 64 + j * 16 + quad * 4;   // < 1536
            int t  = col0 >= 768;
            int cc = col0 - t * 768;
            int h  = cc >> 6, d = cc & 63;
            int f  = h * 192 + t * 64 + d;                      // original feature id
            float4 bb = *(const float4*)(bias + f);
            __bf16* dst = t ? k_out : q_out;
#pragma unroll
            for (int i = 0; i < 4; ++i) {
                long row = bm + wm * 64 + i * 16 + l16;
                long b   = row >> 10;
                long n   = row & 1023;
                bf16x4 pk;
                pk[0] = (__bf16)(acc[i][j][0] + bb.x);
                pk[1] = (__bf16)(acc[i][j][1] + bb.y);
                pk[2] = (__bf16)(acc[i][j][2] + bb.z);
                pk[3] = (__bf16)(acc[i][j][3] + bb.w);
                *(bf16x4*)(dst + ((b * 12 + h) * 1024 + n) * 64 + d) = pk;
            }
        }
    } else if constexpr (MODE == 2) {
        // normal: lane col = d (l16-based), 4 consecutive rows (n) per quad
#pragma unroll
        for (int j = 0; j < 4; ++j) {
            int cv = (int)bn - 1536 + wn * 64 + j * 16 + l16;
            int h  = cv >> 6, d = cv & 63;
            float bv = bias[h * 192 + 128 + d];
#pragma unroll
            for (int i = 0; i < 4; ++i) {
                long row0 = bm + wm * 64 + i * 16 + quad * 4;
                long b    = row0 >> 10;
                long n0   = row0 & 1023;
                bf16x4 pk;
                pk[0] = (__bf16)(acc[i][j][0] + bv);
                pk[1] = (__bf16)(acc[i][j][1] + bv);
                pk[2] = (__bf16)(acc[i][j][2] + bv);
                pk[3] = (__bf16)(acc[i][j][3] + bv);
                *(bf16x4*)(vt_out + ((b * 12 + h) * 64 + d) * 1024 + n0) = pk;
            }
        }
    } else {
#pragma unroll
        for (int i = 0; i < 4; ++i) {
#pragma unroll
            for (int r = 0; r < 4; ++r) {
                long row = bm + wm * 64 + i * 16 + quad * 4 + r;
#pragma unroll
                for (int j = 0; j < 4; ++j) {
                    int col = (int)bn + wn * 64 + j * 16 + l16;
                    f_out[row * 768 + col] = acc[i][j][r] + bias[col];
                }
            }
        }
    }
}

// XCD-aware decode: all blocks sharing one A-tile (by) get the same blk%8
// (same XCD-L2), and within an XCD consecutive blocks walk bx (reuse A-tile).
__global__ __launch_bounds__(256, 3)
void gemm_qkv(const __bf16* __restrict__ A, const __bf16* __restrict__ Bw,
              const float* __restrict__ bias, __bf16* __restrict__ qb,
              __bf16* __restrict__ kb, __bf16* __restrict__ vtb) {
    __shared__ __align__(16) __bf16 As[128 * 32];
    __shared__ __align__(16) __bf16 Bs[128 * 32];
    int blk  = blockIdx.x;            // grid 2304
    int xcd  = blk & 7;
    int rest = blk >> 3;              // 0..287
    int bx   = rest % 18;
    int byg  = rest / 18;             // 0..15
    long by  = xcd + 8 * byg;         // by % 8 == xcd
    if (bx < 12)
        gemm_core<0>(As, Bs, A, Bw, bias, qb, kb, nullptr, nullptr, by * 128, (long)bx * 128);
    else
        gemm_core<2>(As, Bs, A, Bw, bias, nullptr, nullptr, vtb, nullptr, by * 128, (long)bx * 128);
}

__global__ __launch_bounds__(256, 3)
void gemm_proj(const __bf16* __restrict__ A, const __bf16* __restrict__ Bw,
               const float* __restrict__ bias, float* __restrict__ out) {
    __shared__ __align__(16) __bf16 As[128 * 32];
    __shared__ __align__(16) __bf16 Bs[128 * 32];
    int blk  = blockIdx.x;            // grid 768
    int xcd  = blk & 7;
    int rest = blk >> 3;              // 0..95
    int bx   = rest % 6;
    int byg  = rest / 6;              // 0..15
    long by  = xcd + 8 * byg;
    gemm_core<1>(As, Bs, A, Bw, bias, nullptr, nullptr, nullptr, out,
                 by * 128, (long)bx * 128);
}

// ---------------------------------------------------------------- flash attention
// block = (qtile of 64, h, b) via XCD-aware 1D decode: all 16 q-tiles of one
// (b,h) share an XCD (K/V stay L2-resident; staging loads at L2 latency).
// No running max (logits provably small); row-sum deferred. S^T = K*Q^T,
// O^T = V^T*P^T. Q LDS reused as per-wave P. Bias row cached in LDS as f16.
__global__ __launch_bounds__(256, 6)
void attn_kernel(const __bf16* __restrict__ Q, const __bf16* __restrict__ Kb,
                 const __bf16* __restrict__ Vt, const float* __restrict__ biases,
                 __bf16* __restrict__ out) {
    __shared__ __align__(16) __bf16 QPs[64 * 64];  // Q tile, then per-wave P
    __shared__ __align__(16) __bf16 Ks[64 * 64];
    __shared__ __align__(16) __bf16 Vts[64 * 64];  // V^T tile [d][kc]
    __shared__ __align__(16) _Float16 brow[1024];  // attn_biases[h] * log2(e), f16

    const int tid  = threadIdx.x;
    const int lane = tid & 63;
    const int wave = tid >> 6;
    const int quad = lane >> 4;
    const int l16  = lane & 15;
    const int sw   = l16 & 7;

    int blk  = blockIdx.x;            // grid 3072
    int xcd  = blk & 7;
    int rest = blk >> 3;              // 0..383
    int qt   = rest & 15;
    int bhg  = rest >> 4;             // 0..23
    int bh_i = xcd + 8 * bhg;         // 0..191, bh % 8 == xcd
    int b    = bh_i / 12;
    int h    = bh_i - b * 12;

    const long bh = bh_i;
    const __bf16* Qg  = Q  + (bh * 1024 + qt * 64) * 64;
    const __bf16* Kg  = Kb + bh * 1024 * 64;
    const __bf16* Vtg = Vt + bh * 64 * 1024;

    const int e0 = tid, e1 = tid + 256;
    const int r0 = e0 >> 3, c0 = (e0 & 7) ^ (r0 & 7);
    const int r1 = e1 >> 3, c1 = (e1 & 7) ^ (r1 & 7);

    async_cp16((char*)QPs + e0 * 16, Qg + r0 * 64 + c0 * 8);
    async_cp16((char*)QPs + e1 * 16, Qg + r1 * 64 + c1 * 8);
    {
        const float LOG2E = 1.4426950408889634f;
        float4 v = ((const float4*)(biases + (long)h * 1024))[tid];
        h16x4 o;
        o[0] = (_Float16)(v.x * LOG2E); o[1] = (_Float16)(v.y * LOG2E);
        o[2] = (_Float16)(v.z * LOG2E); o[3] = (_Float16)(v.w * LOG2E);
        *(h16x4*)(brow + tid * 4) = o;
    }
    __syncthreads();

    // Q b-frags (lane l16 = q-row wave*16+l16), cached across the loop
    bf16x8 aq[2];
    {
        const u32x4* Qv = (const u32x4*)QPs;
        int qrow = wave * 16 + l16;
        aq[0] = frag_of(Qv[qrow * 8 + (quad ^ sw)]);
        aq[1] = frag_of(Qv[qrow * 8 + ((quad + 4) ^ sw)]);
    }

    // relative-position precompute: yq wave-uniform, xq per-lane (kt-invariant)
    const int yq = 2 * qt + (wave >> 1);
    const int xq = ((wave & 1) << 4) + l16;
    int pdx[2][4];
#pragma unroll
    for (int i2 = 0; i2 < 2; ++i2)
#pragma unroll
        for (int r = 0; r < 4; ++r) {
            int xk = (i2 << 4) + quad * 4 + r;
            int d = xq - xk; pdx[i2][r] = d < 0 ? -d : d;
        }

    const float SSCALE = 0.125f * 1.4426950408889634f;
    float lacc = 0.f;
    f32x4 o[4] = {};
    __bf16* Psw = QPs + wave * 1024;           // 16 rows x 64, per-wave
    const int pwb = l16 * 128 + (quad & 1) * 8; // P-write byte base

    for (int kt = 0; kt < 16; ++kt) {
        __syncthreads();
        {
            const __bf16* Kt  = Kg + kt * 4096;
            const __bf16* Vtt = Vtg + kt * 64;
            async_cp16((char*)Ks + e0 * 16, Kt + r0 * 64 + c0 * 8);
            async_cp16((char*)Ks + e1 * 16, Kt + r1 * 64 + c1 * 8);
            async_cp16((char*)Vts + e0 * 16, Vtt + r0 * 1024 + c0 * 8);
            async_cp16((char*)Vts + e1 * 16, Vtt + r1 * 1024 + c1 * 8);
        }
        __syncthreads();

        // S^T = K * Q^T : s[nt][r] = S[qrow=l16][k = kt*64 + nt*16 + quad*4 + r]
        f32x4 s[4];
        const u32x4* Kv = (const u32x4*)Ks;
#pragma unroll
        for (int nt = 0; nt < 4; ++nt) {
            int krow = nt * 16 + l16;
            bf16x8 k0 = frag_of(Kv[krow * 8 + (quad ^ sw)]);
            bf16x8 k1 = frag_of(Kv[krow * 8 + ((quad + 4) ^ sw)]);
            f32x4 z = {0.f, 0.f, 0.f, 0.f};
            z = __builtin_amdgcn_mfma_f32_16x16x32_bf16(k0, aq[0], z, 0, 0, 0);
            z = __builtin_amdgcn_mfma_f32_16x16x32_bf16(k1, aq[1], z, 0, 0, 0);
            s[nt] = z;
        }

        int dy0 = yq - 2 * kt;     dy0 = dy0 < 0 ? -dy0 : dy0;
        int dy1 = yq - 2 * kt - 1; dy1 = dy1 < 0 ? -dy1 : dy1;
        const _Float16* br0 = brow + dy0 * 32;
        const _Float16* br1 = brow + dy1 * 32;
#pragma unroll
        for (int nt = 0; nt < 4; ++nt) {
            const _Float16* br = (nt & 2) ? br1 : br0;
            bf16x4 pk;
#pragma unroll
            for (int r = 0; r < 4; ++r) {
                float p = __builtin_amdgcn_exp2f(s[nt][r] * SSCALE + (float)br[pdx[nt & 1][r]]);
                lacc += p;
                pk[r] = (__bf16)p;
            }
            *(bf16x4*)((char*)Psw + pwb + (((nt * 2 + (quad >> 1)) ^ sw) << 4)) = pk;
        }

        // O^T = V^T * P^T : o[dt][r] = O[qrow=l16][d = dt*16 + quad*4 + r]
        const u32x4* Pv = (const u32x4*)Psw;
        const u32x4* Vv = (const u32x4*)Vts;
        bf16x8 bp0 = frag_of(Pv[l16 * 8 + (quad ^ sw)]);
        bf16x8 bp1 = frag_of(Pv[l16 * 8 + ((quad + 4) ^ sw)]);
#pragma unroll
        for (int dt = 0; dt < 4; ++dt) {
            int vrow = dt * 16 + l16;
            bf16x8 v0 = frag_of(Vv[vrow * 8 + (quad ^ sw)]);
            bf16x8 v1 = frag_of(Vv[vrow * 8 + ((quad + 4) ^ sw)]);
            o[dt] = __builtin_amdgcn_mfma_f32_16x16x32_bf16(v0, bp0, o[dt], 0, 0, 0);
            o[dt] = __builtin_amdgcn_mfma_f32_16x16x32_bf16(v1, bp1, o[dt], 0, 0, 0);
        }
    }

    // deferred row-sum: combine the 4 quads holding the same q-row
    lacc += __shfl_xor(lacc, 16);
    lacc += __shfl_xor(lacc, 32);
    const float rl = 1.f / lacc;

    const long n = qt * 64 + wave * 16 + l16;
    __bf16* op = out + ((long)b * 1024 + n) * 768 + h * 64 + quad * 4;
#pragma unroll
    for (int dt = 0; dt < 4; ++dt) {
        bf16x4 ov;
        ov[0] = (__bf16)(o[dt][0] * rl);
        ov[1] = (__bf16)(o[dt][1] * rl);
        ov[2] = (__bf16)(o[dt][2] * rl);
        ov[3] = (__bf16)(o[dt][3] * rl);
        *(bf16x4*)(op + dt * 16) = ov;
    }
}

// ---------------------------------------------------------------- launch
extern "C" void kernel_launch(void* const* d_in, const int* in_sizes, int n_in,
                              void* d_out, int out_size, void* d_ws, size_t ws_size,
                              hipStream_t stream) {
    (void)in_sizes; (void)n_in; (void)out_size; (void)ws_size;
    const float* x      = (const float*)d_in[0];
    const float* ln_w   = (const float*)d_in[1];
    const float* ln_b   = (const float*)d_in[2];
    const float* qkv_w  = (const float*)d_in[3];
    const float* qkv_b  = (const float*)d_in[4];
    const float* proj_w = (const float*)d_in[5];
    const float* proj_b = (const float*)d_in[6];
    const float* ab     = (const float*)d_in[7];
    float* outp = (float*)d_out;

    char* ws = (char*)d_ws;
    __bf16* xn     = (__bf16*)(ws);               // reused as attn output
    __bf16* aout   = (__bf16*)(ws);
    __bf16* qkvwb  = (__bf16*)(ws + 25165824);
    __bf16* projwb = (__bf16*)(ws + 28704768);
    __bf16* qb     = (__bf16*)(ws + 29884416);
    __bf16* kb     = (__bf16*)(ws + 55050240);
    __bf16* vtb    = (__bf16*)(ws + 80216064);    // V^T (b,h,d,n), direct from GEMM

    cvt_w<<<2304, 256, 0, stream>>>(qkv_w, proj_w, qkvwb, projwb);
    ln_kernel<<<4096, 256, 0, stream>>>(x, ln_w, ln_b, xn);
    gemm_qkv<<<2304, 256, 0, stream>>>(xn, qkvwb, qkv_b, qb, kb, vtb);
    attn_kernel<<<3072, 256, 0, stream>>>(qb, kb, vtb, ab, aout);
    gemm_proj<<<768, 256, 0, stream>>>(aout, projwb, proj_b, outp);
}